// Round 10
// baseline (16080.078 us; speedup 1.0000x reference)
//
#include <hip/hip_runtime.h>

#define BB 32
#define NN 16384
#define CC 64
#define NC 4096
#define T  1024
#define G  8                    // blocks per batch
#define SLOTS (NN / (G * T))    // 2 points per thread

// ---------------------------------------------------------------------------
// Multi-block FPS: 8 blocks per batch x 32 batches = 256 blocks = 256 CUs.
// Distance chain B1 = fma(dz,dz, fma(dx,dx, dy*dy)) — bitwise-verified vs
// reference (R6). Per-thread state is 8 floats -> pure arch VGPRs.
// Cross-block per-iteration sync: per-iteration ws slots, tag=it+1 packed
// with (val_bits, GLOBAL idx). Slots never overwritten within a replay (no
// ABA); 0xAA poison can't fake a tag (0xAAAA>4095); stale payloads from a
// previous replay are bitwise-identical by determinism.
// R9 crash root cause: reader re-added the block offset to an already-global
// index -> OOB centroid load. Fixed: index is global everywhere.
// Peers of batch b are blockIdx ≡ b (mod 8) -> same XCD round-robin, so the
// spin traffic is L2-local (perf heuristic; agent scope is correct anyway).
// ---------------------------------------------------------------------------

__device__ __forceinline__ unsigned long long ld_acq(const unsigned long long* p) {
    return __hip_atomic_load(p, __ATOMIC_ACQUIRE, __HIP_MEMORY_SCOPE_AGENT);
}
__device__ __forceinline__ void st_rel(unsigned long long* p, unsigned long long v) {
    __hip_atomic_store(p, v, __ATOMIC_RELEASE, __HIP_MEMORY_SCOPE_AGENT);
}

__global__ __launch_bounds__(T, 4) void fps_multi(const float* __restrict__ in,
                                                  float* __restrict__ out,
                                                  unsigned long long* __restrict__ ws) {
#pragma clang fp contract(off)
    const int k    = blockIdx.x;
    const int b    = k & 31;          // batch
    const int g    = k >> 5;          // 0..7 within batch
    const int t    = threadIdx.x;
    const int wave = t >> 6;
    const int lane = t & 63;

    __shared__ float s_wmax[16];
    __shared__ int   s_far2[2];
    __shared__ int   s_next;

    const float* baseb = in + (size_t)b * NN * CC;
    const float* basep = baseb + (size_t)g * (T * SLOTS) * CC;
    const int    goff  = g * (T * SLOTS);

    float px[SLOTS], py[SLOTS], pz[SLOTS], dist[SLOTS];
#pragma unroll
    for (int j = 0; j < SLOTS; ++j) {
        const int i = j * T + t;
        const float4 v = *reinterpret_cast<const float4*>(basep + (size_t)i * CC);
        px[j] = v.x; py[j] = v.y; pz[j] = v.z;
        dist[j] = 1e10f;
    }
    if (t == 0) { s_far2[0] = 0x7fffffff; s_far2[1] = 0x7fffffff; }

    float cx = baseb[0], cy = baseb[1], cz = baseb[2];
    int   far = 0;
    __syncthreads();

    int* idx_out = reinterpret_cast<int*>(out);

    for (int it = 0; it < NC; ++it) {
        if (g == 0 && t == 0) idx_out[((size_t)b * NC + it) * CC] = far;
        if (it == NC - 1) break;

        // ---- dist update (chain B1, bitwise-exact) + value max ----
        float lv = -1.0f;
#pragma unroll
        for (int j = 0; j < SLOTS; ++j) {
            const float dx = px[j] - cx;
            const float dy = py[j] - cy;
            const float dz = pz[j] - cz;
            const float d  = fmaf(dz, dz, fmaf(dx, dx, dy * dy));
            const float nd = fminf(dist[j], d);
            dist[j] = nd;
            lv = fmaxf(lv, nd);
        }

        // ---- wave64 value-max reduce ----
        float wv = lv;
#pragma unroll
        for (int off = 32; off > 0; off >>= 1)
            wv = fmaxf(wv, __shfl_down(wv, off));
        if (lane == 0) s_wmax[wave] = wv;
        if (t == 0) s_far2[(it + 1) & 1] = 0x7fffffff;
        __syncthreads();                                  // A

        // ---- all-thread block max ----
        const float m0 = fmaxf(fmaxf(s_wmax[0],  s_wmax[1]),  fmaxf(s_wmax[2],  s_wmax[3]));
        const float m1 = fmaxf(fmaxf(s_wmax[4],  s_wmax[5]),  fmaxf(s_wmax[6],  s_wmax[7]));
        const float m2 = fmaxf(fmaxf(s_wmax[8],  s_wmax[9]),  fmaxf(s_wmax[10], s_wmax[11]));
        const float m3 = fmaxf(fmaxf(s_wmax[12], s_wmax[13]), fmaxf(s_wmax[14], s_wmax[15]));
        const float gmax = fmaxf(fmaxf(m0, m1), fmaxf(m2, m3));

        // ---- first-occurrence GLOBAL index among achievers ----
        if (lv == gmax) {
            int myi = 0x7fffffff;
#pragma unroll
            for (int j = SLOTS - 1; j >= 0; --j)          // descending: smallest j kept
                myi = (dist[j] == gmax) ? (goff + j * T + t) : myi;
            atomicMin(&s_far2[it & 1], myi);
        }
        __syncthreads();                                  // B

        // ---- publish block partial (tag=it+1 | val_bits | global idx) ----
        if (t == 0) {
            const int bi = s_far2[it & 1];                // global, < 16384
            const unsigned long long pkt =
                ((unsigned long long)(unsigned)(it + 1) << 48) |
                ((unsigned long long)__float_as_uint(gmax) << 16) |
                (unsigned long long)(unsigned)(bi & 0xFFFF);
            st_rel(&ws[(((size_t)it) * BB + b) * G + g], pkt);
        }

        // ---- wave 0: spin on all 8 partials, reduce, broadcast ----
        if (wave == 0) {
            float v  = -1.0f;
            int   vi = 0x7fffffff;
            if (lane < G) {
                const unsigned long long* sp = &ws[(((size_t)it) * BB + b) * G + lane];
                unsigned long long pk;
                do { pk = ld_acq(sp); } while ((int)(pk >> 48) != (it + 1));
                v  = __uint_as_float((unsigned)(pk >> 16));
                vi = (int)(pk & 0xFFFF);                  // global index as published
            }
#pragma unroll
            for (int off = 4; off > 0; off >>= 1) {
                const float ov = __shfl_down(v, off);
                const int   oi = __shfl_down(vi, off);
                const bool better = (ov > v) || (ov == v && oi < vi);
                v  = better ? ov : v;
                vi = better ? oi : vi;
            }
            if (lane == 0) s_next = vi;
        }
        __syncthreads();                                  // C

        far = s_next;
        cx = baseb[(size_t)far * CC + 0];
        cy = baseb[(size_t)far * CC + 1];
        cz = baseb[(size_t)far * CC + 2];
    }
}

// ---------------------------------------------------------------------------
// Fallback single-block FPS (R7, 6.68 ms) — used only if ws too small.
// ---------------------------------------------------------------------------
#define FSLOTS 16
__global__ __launch_bounds__(T, 4) void fps_single(const float* __restrict__ in,
                                                   float* __restrict__ out) {
#pragma clang fp contract(off)
    const int b    = blockIdx.x;
    const int t    = threadIdx.x;
    const int wave = t >> 6;
    const int lane = t & 63;

    __shared__ float s_wmax[16];
    __shared__ float s_cx, s_cy, s_cz;
    __shared__ int   s_far2[2];

    const float* base = in + (size_t)b * NN * CC;

    float px[FSLOTS], py[FSLOTS], pz[FSLOTS], dist[FSLOTS];
#pragma unroll
    for (int j = 0; j < FSLOTS; ++j) {
        const int i = j * T + t;
        const float4 v = *reinterpret_cast<const float4*>(base + (size_t)i * CC);
        px[j] = v.x; py[j] = v.y; pz[j] = v.z;
        dist[j] = 1e10f;
    }
    if (t == 0) { s_far2[0] = 0x7fffffff; s_far2[1] = 0x7fffffff; }

    float cx = base[0], cy = base[1], cz = base[2];
    int   far = 0;
    __syncthreads();

    int* idx_out = reinterpret_cast<int*>(out);

    for (int it = 0; it < NC; ++it) {
        if (t == 0) idx_out[((size_t)b * NC + it) * CC] = far;
        if (it == NC - 1) break;

        float lv = -1.0f;
#pragma unroll
        for (int j = 0; j < FSLOTS; ++j) {
            const float dx = px[j] - cx;
            const float dy = py[j] - cy;
            const float dz = pz[j] - cz;
            const float d  = fmaf(dz, dz, fmaf(dx, dx, dy * dy));
            const float nd = fminf(dist[j], d);
            dist[j] = nd;
            lv = fmaxf(lv, nd);
        }

        float wv = lv;
#pragma unroll
        for (int off = 32; off > 0; off >>= 1)
            wv = fmaxf(wv, __shfl_down(wv, off));
        if (lane == 0) s_wmax[wave] = wv;
        if (t == 0) s_far2[(it + 1) & 1] = 0x7fffffff;
        __syncthreads();

        const float m0 = fmaxf(fmaxf(s_wmax[0],  s_wmax[1]),  fmaxf(s_wmax[2],  s_wmax[3]));
        const float m1 = fmaxf(fmaxf(s_wmax[4],  s_wmax[5]),  fmaxf(s_wmax[6],  s_wmax[7]));
        const float m2 = fmaxf(fmaxf(s_wmax[8],  s_wmax[9]),  fmaxf(s_wmax[10], s_wmax[11]));
        const float m3 = fmaxf(fmaxf(s_wmax[12], s_wmax[13]), fmaxf(s_wmax[14], s_wmax[15]));
        const float gmax = fmaxf(fmaxf(m0, m1), fmaxf(m2, m3));

        if (lv == gmax) {
            int myi = 0x7fffffff;
#pragma unroll
            for (int j = FSLOTS - 1; j >= 0; --j)
                myi = (dist[j] == gmax) ? (j * T + t) : myi;
            atomicMin(&s_far2[it & 1], myi);
        }
        __syncthreads();

        far = s_far2[it & 1];

        if ((far & (T - 1)) == t) {
            const int jj = far >> 10;
            float x = px[0], y = py[0], z = pz[0];
#pragma unroll
            for (int kk = 1; kk < FSLOTS; ++kk) {
                const bool c = (jj == kk);
                x = c ? px[kk] : x;
                y = c ? py[kk] : y;
                z = c ? pz[kk] : z;
            }
            s_cx = x; s_cy = y; s_cz = z;
        }
        __syncthreads();
        cx = s_cx; cy = s_cy; cz = s_cz;
    }
}

// ---------------------------------------------------------------------------
// Gather kernel: one wave64 per output row (64 channels).
// ---------------------------------------------------------------------------
__global__ __launch_bounds__(256) void gather_kernel(const float* __restrict__ in,
                                                     float* out) {
    const int gid  = blockIdx.x * blockDim.x + threadIdx.x;
    const int row  = gid >> 6;
    const int lane = gid & 63;
    const int b = row >> 12;       // NC == 4096
    const int idx = reinterpret_cast<const int*>(out)[(size_t)row * CC];
    const float v = in[((size_t)b * NN + idx) * CC + lane];
    out[(size_t)row * CC + lane] = v;
}

extern "C" void kernel_launch(void* const* d_in, const int* in_sizes, int n_in,
                              void* d_out, int out_size, void* d_ws, size_t ws_size,
                              hipStream_t stream) {
    const float* in = (const float*)d_in[0];
    float* out = (float*)d_out;

    const size_t ws_need = (size_t)NC * BB * G * sizeof(unsigned long long); // 8 MB
    if (ws_size >= ws_need) {
        fps_multi<<<BB * G, T, 0, stream>>>(in, out, (unsigned long long*)d_ws);
    } else {
        fps_single<<<BB, T, 0, stream>>>(in, out);
    }

    const int total = BB * NC * CC;          // 8,388,608
    gather_kernel<<<total / 256, 256, 0, stream>>>(in, out);
}

// Round 11
// 6895.255 us; speedup vs baseline: 2.3320x; 2.3320x over previous
//
#include <hip/hip_runtime.h>

#define BB 32
#define NN 16384
#define CC 64
#define NC 4096
#define T  512             // threads per FPS block (8 waves = 2/SIMD -> 256 VGPR budget)
#define SLOTS (NN / T)     // 32 points per thread
#define PAIRS (SLOTS / 2)  // 16 float2 pairs

typedef float f2 __attribute__((ext_vector_type(2)));

// ---------------------------------------------------------------------------
// Single-block-per-batch FPS, packed-fp32 state.
// R10 showed cross-block sync costs ~4.6us/iter (agent-scope spin round-trips
// L3/HBM across non-coherent XCD L2s) -> multi-block is structurally dead.
// R8 showed packed f2 state at T=1024 spills to scratch (128-reg cap).
// Fix: T=512 + __launch_bounds__(512,2) -> 256 VGPR budget; 128 regs of f2
// state (px,py,pz,dist) + temps fit in arch VGPRs; v_pk_{add,mul,fma}_f32
// does 2 points per issue. Packed arithmetic bitwise-verified in R8 (passed).
// Distance chain B1 = fma(dz,dz, fma(dx,dx, dy*dy)) — bitwise vs ref (R6).
// Argmax: value-only reduce (wave shfl -> 8 LDS partials -> all-thread max),
// then matching threads rescan descending (first-occurrence) + atomicMin
// (= numpy argmax semantics, verified R7/R8).
// 2 barriers/iter; centroid re-read as uniform global load (L1 broadcast);
// 4-deep sentinel rotation makes the 2-barrier loop formally race-free:
// buffer q is written/read at iters ≡ q (mod 4) and reset at iters ≡ q+1,
// with barrier B separating the reset from the preceding read.
// ---------------------------------------------------------------------------
__global__ __launch_bounds__(T, 2) void fps_kernel(const float* __restrict__ in,
                                                   float* __restrict__ out) {
#pragma clang fp contract(off)
    const int b    = blockIdx.x;
    const int t    = threadIdx.x;
    const int wave = t >> 6;
    const int lane = t & 63;

    __shared__ float s_wmax[8];
    __shared__ int   s_far4[4];

    const float* base = in + (size_t)b * NN * CC;

    f2 px[PAIRS], py[PAIRS], pz[PAIRS], dist[PAIRS];
#pragma unroll
    for (int k = 0; k < PAIRS; ++k) {
        const int i0 = (2 * k) * T + t;
        const int i1 = (2 * k + 1) * T + t;
        const float4 v0 = *reinterpret_cast<const float4*>(base + (size_t)i0 * CC);
        const float4 v1 = *reinterpret_cast<const float4*>(base + (size_t)i1 * CC);
        px[k] = f2{v0.x, v1.x};
        py[k] = f2{v0.y, v1.y};
        pz[k] = f2{v0.z, v1.z};
        dist[k] = f2{1e10f, 1e10f};
    }
    if (t < 4) s_far4[t] = 0x7fffffff;

    float cx = base[0], cy = base[1], cz = base[2];   // point 0
    int   far = 0;
    __syncthreads();

    int* idx_out = reinterpret_cast<int*>(out);

    for (int it = 0; it < NC; ++it) {
        if (t == 0) idx_out[((size_t)b * NC + it) * CC] = far;
        if (it == NC - 1) break;

        // ---- packed dist update (chain B1) + packed running max ----
        const f2 cx2 = f2{cx, cx}, cy2 = f2{cy, cy}, cz2 = f2{cz, cz};
        f2 mx = f2{-1.0f, -1.0f};
#pragma unroll
        for (int k = 0; k < PAIRS; ++k) {
            const f2 dx = px[k] - cx2;
            const f2 dy = py[k] - cy2;
            const f2 dz = pz[k] - cz2;
            const f2 d  = __builtin_elementwise_fma(dz, dz,
                            __builtin_elementwise_fma(dx, dx, dy * dy));
            const f2 nd = __builtin_elementwise_min(dist[k], d);
            dist[k] = nd;
            mx = __builtin_elementwise_max(mx, nd);
        }
        const float lv = fmaxf(mx.x, mx.y);

        // ---- wave64 value-max reduce ----
        float wv = lv;
#pragma unroll
        for (int off = 32; off > 0; off >>= 1)
            wv = fmaxf(wv, __shfl_down(wv, off));
        if (lane == 0) s_wmax[wave] = wv;
        if (t == 0) s_far4[(it + 3) & 3] = 0x7fffffff;   // rotate sentinel
        __syncthreads();                                  // A

        // ---- all-thread block max over 8 wave partials ----
        const float g0 = fmaxf(fmaxf(s_wmax[0], s_wmax[1]), fmaxf(s_wmax[2], s_wmax[3]));
        const float g1 = fmaxf(fmaxf(s_wmax[4], s_wmax[5]), fmaxf(s_wmax[6], s_wmax[7]));
        const float gmax = fmaxf(g0, g1);

        // ---- matching threads: first local index (descending), atomicMin ----
        if (lv == gmax) {
            int myi = 0x7fffffff;
#pragma unroll
            for (int j = SLOTS - 1; j >= 0; --j) {       // constant idx after unroll
                const float dj = (j & 1) ? dist[j >> 1].y : dist[j >> 1].x;
                myi = (dj == gmax) ? (j * T + t) : myi;
            }
            atomicMin(&s_far4[it & 3], myi);
        }
        __syncthreads();                                  // B

        far = __builtin_amdgcn_readfirstlane(s_far4[it & 3]);

        // ---- uniform centroid reload (L1 broadcast; exact input bits) ----
        cx = base[(size_t)far * CC + 0];
        cy = base[(size_t)far * CC + 1];
        cz = base[(size_t)far * CC + 2];
    }
}

// ---------------------------------------------------------------------------
// Gather kernel: one wave64 per output row (64 channels). Reads the stored
// index (int at channel 0 of the row), then copies the full input row.
// ---------------------------------------------------------------------------
__global__ __launch_bounds__(256) void gather_kernel(const float* __restrict__ in,
                                                     float* out) {
    const int gid  = blockIdx.x * blockDim.x + threadIdx.x;
    const int row  = gid >> 6;     // 0 .. B*NC-1
    const int lane = gid & 63;     // channel
    const int b = row >> 12;       // NC == 4096
    const int idx = reinterpret_cast<const int*>(out)[(size_t)row * CC];
    const float v = in[((size_t)b * NN + idx) * CC + lane];
    out[(size_t)row * CC + lane] = v;
}

extern "C" void kernel_launch(void* const* d_in, const int* in_sizes, int n_in,
                              void* d_out, int out_size, void* d_ws, size_t ws_size,
                              hipStream_t stream) {
    const float* in = (const float*)d_in[0];
    float* out = (float*)d_out;

    fps_kernel<<<BB, T, 0, stream>>>(in, out);

    const int total = BB * NC * CC;          // 8,388,608
    gather_kernel<<<total / 256, 256, 0, stream>>>(in, out);
}

// Round 12
// 6478.196 us; speedup vs baseline: 2.4822x; 1.0644x over previous
//
#include <hip/hip_runtime.h>

#define BB 32
#define NN 16384
#define CC 64
#define NC 4096
#define T  512             // 8 waves = 2/SIMD -> 256 unified regs/wave budget
#define SLOTS (NN / T)     // 32 points per thread
#define PAIRS (SLOTS / 2)  // 16 float2 pairs

typedef float f2 __attribute__((ext_vector_type(2)));

// ---------------------------------------------------------------------------
// FPS, single block per batch (R10 proved cross-block sync ~4.6us/iter: dead).
// Distance chain B1 = fma(dz,dz, fma(dx,dx, dy*dy)) — bitwise-verified (R6).
// R12 changes vs R11 (both latency attacks, structure identical):
//  1. xyz compacted into d_ws (12B/point, 192KB/batch -> L2-resident): the
//     per-iteration uniform centroid reload becomes an L2 hit (~200cyc) not
//     an HBM miss (~900cyc). R11 FETCH showed +6MB of line-granular centroid
//     reads. Bits are exact copies, so arithmetic is unchanged.
//  2. empty asm "+v" pins on every px/py/pz/dist use in the update loop:
//     forces regalloc to home the state in arch VGPRs. R11 had VGPR_Count=84
//     for 128+ regs of state => AGPR homing + ~190 accvgpr moves per iter
//     (R7 same disease; R8's scratch variant was worse). VOP3P can't read
//     AGPRs, so pinned-VGPR homes make the packed ops move-free.
// Argmax: value-only packed max -> wave shfl reduce -> 8 LDS partials ->
// all-thread max -> achievers rescan descending + atomicMin (first-occurrence
// == numpy argmax; verified R7/R8/R11). 2 barriers/iter, 4-deep sentinel
// rotation (reset of buffer q+3 is barrier-separated from its uses).
// ---------------------------------------------------------------------------
__global__ __launch_bounds__(T, 2) void fps_kernel(const float* __restrict__ in,
                                                   float* __restrict__ out,
                                                   const float* __restrict__ cpts) {
#pragma clang fp contract(off)
    const int b    = blockIdx.x;
    const int t    = threadIdx.x;
    const int wave = t >> 6;
    const int lane = t & 63;

    __shared__ float s_wmax[8];
    __shared__ int   s_far4[4];

    const float* cb = cpts + (size_t)b * NN * 3;     // compact xyz rows (12B)

    f2 px[PAIRS], py[PAIRS], pz[PAIRS], dist[PAIRS];
#pragma unroll
    for (int k = 0; k < PAIRS; ++k) {
        const int i0 = (2 * k) * T + t;
        const int i1 = (2 * k + 1) * T + t;
        px[k]   = f2{cb[i0 * 3 + 0], cb[i1 * 3 + 0]};
        py[k]   = f2{cb[i0 * 3 + 1], cb[i1 * 3 + 1]};
        pz[k]   = f2{cb[i0 * 3 + 2], cb[i1 * 3 + 2]};
        dist[k] = f2{1e10f, 1e10f};
    }
    if (t < 4) s_far4[t] = 0x7fffffff;

    float cx = cb[0], cy = cb[1], cz = cb[2];        // point 0
    int   far = 0;
    __syncthreads();

    int* idx_out = reinterpret_cast<int*>(out);

    for (int it = 0; it < NC; ++it) {
        if (t == 0) idx_out[((size_t)b * NC + it) * CC] = far;
        if (it == NC - 1) break;

        // ---- packed dist update (chain B1) + packed running max ----
        const f2 cx2 = f2{cx, cx}, cy2 = f2{cy, cy}, cz2 = f2{cz, cz};
        f2 mx = f2{-1.0f, -1.0f};
#pragma unroll
        for (int k = 0; k < PAIRS; ++k) {
            asm("" : "+v"(px[k]));                   // pin state to arch VGPRs
            asm("" : "+v"(py[k]));
            asm("" : "+v"(pz[k]));
            asm("" : "+v"(dist[k]));
            const f2 dx = px[k] - cx2;
            const f2 dy = py[k] - cy2;
            const f2 dz = pz[k] - cz2;
            const f2 d  = __builtin_elementwise_fma(dz, dz,
                            __builtin_elementwise_fma(dx, dx, dy * dy));
            const f2 nd = __builtin_elementwise_min(dist[k], d);
            dist[k] = nd;
            mx = __builtin_elementwise_max(mx, nd);
        }
        const float lv = fmaxf(mx.x, mx.y);

        // ---- wave64 value-max reduce ----
        float wv = lv;
#pragma unroll
        for (int off = 32; off > 0; off >>= 1)
            wv = fmaxf(wv, __shfl_down(wv, off));
        if (lane == 0) s_wmax[wave] = wv;
        if (t == 0) s_far4[(it + 3) & 3] = 0x7fffffff;   // rotate sentinel
        __syncthreads();                                  // A

        // ---- all-thread block max over 8 wave partials ----
        const float g0 = fmaxf(fmaxf(s_wmax[0], s_wmax[1]), fmaxf(s_wmax[2], s_wmax[3]));
        const float g1 = fmaxf(fmaxf(s_wmax[4], s_wmax[5]), fmaxf(s_wmax[6], s_wmax[7]));
        const float gmax = fmaxf(g0, g1);

        // ---- achievers: first local index (descending), atomicMin ----
        if (lv == gmax) {
            int myi = 0x7fffffff;
#pragma unroll
            for (int j = SLOTS - 1; j >= 0; --j) {
                const float dj = (j & 1) ? dist[j >> 1].y : dist[j >> 1].x;
                myi = (dj == gmax) ? (j * T + t) : myi;
            }
            atomicMin(&s_far4[it & 3], myi);
        }
        __syncthreads();                                  // B

        far = s_far4[it & 3];

        // ---- centroid reload from compact L2-resident buffer ----
        cx = cb[(size_t)far * 3 + 0];
        cy = cb[(size_t)far * 3 + 1];
        cz = cb[(size_t)far * 3 + 2];
    }
}

// ---------------------------------------------------------------------------
// One-time xyz compaction: in[b][i][0..2] -> cpts[b][i*3+{0,1,2}] (12B rows).
// ---------------------------------------------------------------------------
__global__ __launch_bounds__(256) void compact_kernel(const float* __restrict__ in,
                                                      float* __restrict__ cpts) {
    const int gid = blockIdx.x * blockDim.x + threadIdx.x;   // one point each
    const int b   = gid >> 14;                               // NN == 16384
    const int i   = gid & (NN - 1);
    const float* src = in + ((size_t)b * NN + i) * CC;
    float* dst = cpts + ((size_t)b * NN + i) * 3;
    dst[0] = src[0];
    dst[1] = src[1];
    dst[2] = src[2];
}

// ---------------------------------------------------------------------------
// Gather kernel: one wave64 per output row (64 channels). Reads the stored
// index (int at channel 0 of the row), then copies the full input row.
// ---------------------------------------------------------------------------
__global__ __launch_bounds__(256) void gather_kernel(const float* __restrict__ in,
                                                     float* out) {
    const int gid  = blockIdx.x * blockDim.x + threadIdx.x;
    const int row  = gid >> 6;     // 0 .. B*NC-1
    const int lane = gid & 63;     // channel
    const int b = row >> 12;       // NC == 4096
    const int idx = reinterpret_cast<const int*>(out)[(size_t)row * CC];
    const float v = in[((size_t)b * NN + idx) * CC + lane];
    out[(size_t)row * CC + lane] = v;
}

// ---------------------------------------------------------------------------
// Fallback (ws too small): R11 kernel reading strided input directly.
// ---------------------------------------------------------------------------
__global__ __launch_bounds__(T, 2) void fps_fallback(const float* __restrict__ in,
                                                     float* __restrict__ out) {
#pragma clang fp contract(off)
    const int b    = blockIdx.x;
    const int t    = threadIdx.x;
    const int wave = t >> 6;
    const int lane = t & 63;

    __shared__ float s_wmax[8];
    __shared__ int   s_far4[4];

    const float* base = in + (size_t)b * NN * CC;

    f2 px[PAIRS], py[PAIRS], pz[PAIRS], dist[PAIRS];
#pragma unroll
    for (int k = 0; k < PAIRS; ++k) {
        const int i0 = (2 * k) * T + t;
        const int i1 = (2 * k + 1) * T + t;
        const float4 v0 = *reinterpret_cast<const float4*>(base + (size_t)i0 * CC);
        const float4 v1 = *reinterpret_cast<const float4*>(base + (size_t)i1 * CC);
        px[k] = f2{v0.x, v1.x};
        py[k] = f2{v0.y, v1.y};
        pz[k] = f2{v0.z, v1.z};
        dist[k] = f2{1e10f, 1e10f};
    }
    if (t < 4) s_far4[t] = 0x7fffffff;

    float cx = base[0], cy = base[1], cz = base[2];
    int   far = 0;
    __syncthreads();

    int* idx_out = reinterpret_cast<int*>(out);

    for (int it = 0; it < NC; ++it) {
        if (t == 0) idx_out[((size_t)b * NC + it) * CC] = far;
        if (it == NC - 1) break;

        const f2 cx2 = f2{cx, cx}, cy2 = f2{cy, cy}, cz2 = f2{cz, cz};
        f2 mx = f2{-1.0f, -1.0f};
#pragma unroll
        for (int k = 0; k < PAIRS; ++k) {
            const f2 dx = px[k] - cx2;
            const f2 dy = py[k] - cy2;
            const f2 dz = pz[k] - cz2;
            const f2 d  = __builtin_elementwise_fma(dz, dz,
                            __builtin_elementwise_fma(dx, dx, dy * dy));
            const f2 nd = __builtin_elementwise_min(dist[k], d);
            dist[k] = nd;
            mx = __builtin_elementwise_max(mx, nd);
        }
        const float lv = fmaxf(mx.x, mx.y);

        float wv = lv;
#pragma unroll
        for (int off = 32; off > 0; off >>= 1)
            wv = fmaxf(wv, __shfl_down(wv, off));
        if (lane == 0) s_wmax[wave] = wv;
        if (t == 0) s_far4[(it + 3) & 3] = 0x7fffffff;
        __syncthreads();

        const float g0 = fmaxf(fmaxf(s_wmax[0], s_wmax[1]), fmaxf(s_wmax[2], s_wmax[3]));
        const float g1 = fmaxf(fmaxf(s_wmax[4], s_wmax[5]), fmaxf(s_wmax[6], s_wmax[7]));
        const float gmax = fmaxf(g0, g1);

        if (lv == gmax) {
            int myi = 0x7fffffff;
#pragma unroll
            for (int j = SLOTS - 1; j >= 0; --j) {
                const float dj = (j & 1) ? dist[j >> 1].y : dist[j >> 1].x;
                myi = (dj == gmax) ? (j * T + t) : myi;
            }
            atomicMin(&s_far4[it & 3], myi);
        }
        __syncthreads();

        far = s_far4[it & 3];
        cx = base[(size_t)far * CC + 0];
        cy = base[(size_t)far * CC + 1];
        cz = base[(size_t)far * CC + 2];
    }
}

extern "C" void kernel_launch(void* const* d_in, const int* in_sizes, int n_in,
                              void* d_out, int out_size, void* d_ws, size_t ws_size,
                              hipStream_t stream) {
    const float* in = (const float*)d_in[0];
    float* out = (float*)d_out;

    const size_t ws_need = (size_t)BB * NN * 3 * sizeof(float);   // 6 MB
    if (ws_size >= ws_need) {
        float* cpts = (float*)d_ws;
        compact_kernel<<<(BB * NN) / 256, 256, 0, stream>>>(in, cpts);
        fps_kernel<<<BB, T, 0, stream>>>(in, out, cpts);
    } else {
        fps_fallback<<<BB, T, 0, stream>>>(in, out);
    }

    const int total = BB * NC * CC;          // 8,388,608
    gather_kernel<<<total / 256, 256, 0, stream>>>(in, out);
}

// Round 14
// 5325.064 us; speedup vs baseline: 3.0197x; 1.2165x over previous
//
#include <hip/hip_runtime.h>

#define BB 32
#define NN 16384
#define CC 64
#define NC 4096
#define T  512             // 8 waves = 2/SIMD -> 256 unified regs/wave budget
#define SLOTS (NN / T)     // 32 points per thread

// ---------------------------------------------------------------------------
// FPS, one block per batch (R10: cross-block sync ~4.6us/iter via L3 = dead).
// Distance chain B1 = fma(dz,dz, fma(dx,dx, dy*dy)) — bitwise-verified (R6).
// R14 = R13 with the DPP ctrl as a template parameter (builtin requires a
// constant integer; R13 passed it via a runtime function arg -> compile fail).
//  - scalar float arrays (R7-proven codegen) at T=512/(512,2): 256-reg budget
//    so the 128-float state can live in arch VGPRs.
//  - wave max via DPP (row_shr 1/2/4/8 + row_bcast 15/31): ~6 VALU insts vs
//    6 chained ds_bpermute (~120cyc each) for __shfl_down. Valid: all lv>=0,
//    bound_ctrl zero-fill is neutral for max.
//  - cross-wave combine via single LDS atomicMax on float bits (dist>=0 =>
//    IEEE bit order == float order), replacing the 8-partial LDS tree.
//  - sentinel rotation depth 4, reset slot (it+2)&3: every reset is separated
//    from that slot's previous read and next write by >=2 barriers.
// Argmax ties: value-only reduce, achievers rescan descending (first
// occurrence) + atomicMin = numpy argmax semantics (verified R7-R12).
// Centroid reload from compact 12B-row buffer in d_ws (L2-resident; R12
// measured FETCH 38.7->3.1MB).
// ---------------------------------------------------------------------------

template <int CTRL>
__device__ __forceinline__ float dpp_max(float x) {
    const int yi = __builtin_amdgcn_update_dpp(0, __float_as_int(x),
                                               CTRL, 0xf, 0xf, true);
    return fmaxf(x, __int_as_float(yi));
}

__device__ __forceinline__ float wave_max_dpp(float x) {
    x = dpp_max<0x111>(x);   // row_shr:1
    x = dpp_max<0x112>(x);   // row_shr:2
    x = dpp_max<0x114>(x);   // row_shr:4
    x = dpp_max<0x118>(x);   // row_shr:8
    x = dpp_max<0x142>(x);   // row_bcast:15
    x = dpp_max<0x143>(x);   // row_bcast:31
    return x;                // valid in lane 63
}

__global__ __launch_bounds__(T, 2) void fps_kernel(const float* __restrict__ in,
                                                   float* __restrict__ out,
                                                   const float* __restrict__ cpts) {
#pragma clang fp contract(off)
    const int b    = blockIdx.x;
    const int t    = threadIdx.x;
    const int lane = t & 63;

    __shared__ unsigned s_gbits4[4];
    __shared__ int      s_far4[4];

    const float* base = in + (size_t)b * NN * CC;
    const float* cb   = cpts + (size_t)b * NN * 3;

    float px[SLOTS], py[SLOTS], pz[SLOTS], dist[SLOTS];
#pragma unroll
    for (int j = 0; j < SLOTS; ++j) {
        const int i = j * T + t;
        const float4 v = *reinterpret_cast<const float4*>(base + (size_t)i * CC);
        px[j] = v.x; py[j] = v.y; pz[j] = v.z;
        dist[j] = 1e10f;
    }
    if (t < 4) { s_far4[t] = 0x7fffffff; s_gbits4[t] = 0u; }

    float cx = base[0], cy = base[1], cz = base[2];   // point 0
    int   far = 0;
    __syncthreads();

    int* idx_out = reinterpret_cast<int*>(out);

    for (int it = 0; it < NC; ++it) {
        if (t == 0) idx_out[((size_t)b * NC + it) * CC] = far;
        if (it == NC - 1) break;

        // ---- dist update (chain B1, bitwise-exact) + running value max ----
        float lv = -1.0f;
#pragma unroll
        for (int j = 0; j < SLOTS; ++j) {
            const float dx = px[j] - cx;
            const float dy = py[j] - cy;
            const float dz = pz[j] - cz;
            const float d  = fmaf(dz, dz, fmaf(dx, dx, dy * dy));
            const float nd = fminf(dist[j], d);
            dist[j] = nd;
            lv = fmaxf(lv, nd);
        }

        // ---- wave64 max via DPP; lane 63 -> LDS atomicMax on bits ----
        const float wv = wave_max_dpp(lv);
        if (lane == 63)
            atomicMax(&s_gbits4[it & 3], __float_as_uint(wv));

        if (t == 0) {              // reset slot used 2 iters ahead (barrier-safe)
            s_far4[(it + 2) & 3]   = 0x7fffffff;
            s_gbits4[(it + 2) & 3] = 0u;
        }
        __syncthreads();                                  // A

        const float gm = __uint_as_float(s_gbits4[it & 3]);

        // ---- achievers: first local index (descending), atomicMin ----
        if (lv == gm) {
            int myi = 0x7fffffff;
#pragma unroll
            for (int j = SLOTS - 1; j >= 0; --j)
                myi = (dist[j] == gm) ? (j * T + t) : myi;
            atomicMin(&s_far4[it & 3], myi);
        }
        __syncthreads();                                  // B

        far = s_far4[it & 3];

        // ---- centroid reload from compact L2-resident buffer ----
        cx = cb[(size_t)far * 3 + 0];
        cy = cb[(size_t)far * 3 + 1];
        cz = cb[(size_t)far * 3 + 2];
    }
}

// ---------------------------------------------------------------------------
// One-time xyz compaction: in[b][i][0..2] -> cpts[b][i*3+{0,1,2}] (12B rows).
// ---------------------------------------------------------------------------
__global__ __launch_bounds__(256) void compact_kernel(const float* __restrict__ in,
                                                      float* __restrict__ cpts) {
    const int gid = blockIdx.x * blockDim.x + threadIdx.x;   // one point each
    const int b   = gid >> 14;                               // NN == 16384
    const int i   = gid & (NN - 1);
    const float* src = in + ((size_t)b * NN + i) * CC;
    float* dst = cpts + ((size_t)b * NN + i) * 3;
    dst[0] = src[0];
    dst[1] = src[1];
    dst[2] = src[2];
}

// ---------------------------------------------------------------------------
// Fallback (ws too small): same kernel but centroid reloads hit the strided
// input directly (R11 behavior, ~0.4ms slower).
// ---------------------------------------------------------------------------
__global__ __launch_bounds__(T, 2) void fps_fallback(const float* __restrict__ in,
                                                     float* __restrict__ out) {
#pragma clang fp contract(off)
    const int b    = blockIdx.x;
    const int t    = threadIdx.x;
    const int lane = t & 63;

    __shared__ unsigned s_gbits4[4];
    __shared__ int      s_far4[4];

    const float* base = in + (size_t)b * NN * CC;

    float px[SLOTS], py[SLOTS], pz[SLOTS], dist[SLOTS];
#pragma unroll
    for (int j = 0; j < SLOTS; ++j) {
        const int i = j * T + t;
        const float4 v = *reinterpret_cast<const float4*>(base + (size_t)i * CC);
        px[j] = v.x; py[j] = v.y; pz[j] = v.z;
        dist[j] = 1e10f;
    }
    if (t < 4) { s_far4[t] = 0x7fffffff; s_gbits4[t] = 0u; }

    float cx = base[0], cy = base[1], cz = base[2];
    int   far = 0;
    __syncthreads();

    int* idx_out = reinterpret_cast<int*>(out);

    for (int it = 0; it < NC; ++it) {
        if (t == 0) idx_out[((size_t)b * NC + it) * CC] = far;
        if (it == NC - 1) break;

        float lv = -1.0f;
#pragma unroll
        for (int j = 0; j < SLOTS; ++j) {
            const float dx = px[j] - cx;
            const float dy = py[j] - cy;
            const float dz = pz[j] - cz;
            const float d  = fmaf(dz, dz, fmaf(dx, dx, dy * dy));
            const float nd = fminf(dist[j], d);
            dist[j] = nd;
            lv = fmaxf(lv, nd);
        }

        const float wv = wave_max_dpp(lv);
        if (lane == 63)
            atomicMax(&s_gbits4[it & 3], __float_as_uint(wv));

        if (t == 0) {
            s_far4[(it + 2) & 3]   = 0x7fffffff;
            s_gbits4[(it + 2) & 3] = 0u;
        }
        __syncthreads();

        const float gm = __uint_as_float(s_gbits4[it & 3]);

        if (lv == gm) {
            int myi = 0x7fffffff;
#pragma unroll
            for (int j = SLOTS - 1; j >= 0; --j)
                myi = (dist[j] == gm) ? (j * T + t) : myi;
            atomicMin(&s_far4[it & 3], myi);
        }
        __syncthreads();

        far = s_far4[it & 3];
        cx = base[(size_t)far * CC + 0];
        cy = base[(size_t)far * CC + 1];
        cz = base[(size_t)far * CC + 2];
    }
}

// ---------------------------------------------------------------------------
// Gather kernel: one wave64 per output row (64 channels).
// ---------------------------------------------------------------------------
__global__ __launch_bounds__(256) void gather_kernel(const float* __restrict__ in,
                                                     float* out) {
    const int gid  = blockIdx.x * blockDim.x + threadIdx.x;
    const int row  = gid >> 6;     // 0 .. B*NC-1
    const int lane = gid & 63;     // channel
    const int b = row >> 12;       // NC == 4096
    const int idx = reinterpret_cast<const int*>(out)[(size_t)row * CC];
    const float v = in[((size_t)b * NN + idx) * CC + lane];
    out[(size_t)row * CC + lane] = v;
}

extern "C" void kernel_launch(void* const* d_in, const int* in_sizes, int n_in,
                              void* d_out, int out_size, void* d_ws, size_t ws_size,
                              hipStream_t stream) {
    const float* in = (const float*)d_in[0];
    float* out = (float*)d_out;

    const size_t ws_need = (size_t)BB * NN * 3 * sizeof(float);   // 6 MB
    if (ws_size >= ws_need) {
        float* cpts = (float*)d_ws;
        compact_kernel<<<(BB * NN) / 256, 256, 0, stream>>>(in, cpts);
        fps_kernel<<<BB, T, 0, stream>>>(in, out, cpts);
    } else {
        fps_fallback<<<BB, T, 0, stream>>>(in, out);
    }

    const int total = BB * NC * CC;          // 8,388,608
    gather_kernel<<<total / 256, 256, 0, stream>>>(in, out);
}